// Round 6
// baseline (249.496 us; speedup 1.0000x reference)
//
#include <hip/hip_runtime.h>
#include <math.h>

#define EE 5120
#define DD 2560
#define BB 32

typedef __attribute__((ext_vector_type(8)))  short  short8;
typedef __attribute__((ext_vector_type(8)))  __bf16 bf16x8;
typedef __attribute__((ext_vector_type(16))) float  f32x16;

// Split fp32 into bf16 hi (truncate) + bf16 lo (truncate of exact residual).
__device__ __forceinline__ void split8(const float* v, short8& hi, short8& lo) {
#pragma unroll
  for (int j = 0; j < 8; ++j) {
    unsigned u = __float_as_uint(v[j]);
    hi[j] = (short)(u >> 16);
    float r = v[j] - __uint_as_float(u & 0xFFFF0000u);
    lo[j] = (short)(__float_as_uint(r) >> 16);
  }
}
#define BC(x) __builtin_bit_cast(bf16x8, x)

// Async global->LDS DMA, 16B per lane (used by k3).
__device__ __forceinline__ void g2l16(const float* g, float* l) {
  __builtin_amdgcn_global_load_lds(
      (const __attribute__((address_space(1))) void*)g,
      (__attribute__((address_space(3))) void*)l, 16, 0, 0);
}

// ---------------------------------------------------------------------------
// K0: transpose x (B,D) -> xT (D,B); zero dbc accumulator.
__global__ __launch_bounds__(256) void k0_prep(const float* __restrict__ x,
                                               float* __restrict__ xT,
                                               float* __restrict__ dbc) {
  int g = blockIdx.x * 256 + threadIdx.x;
  if (g < BB * DD) {
    int b = g / DD, k = g % DD;
    xT[k * BB + b] = x[g];
  }
  if (g < BB * 192) dbc[g] = 0.f;
}

// ---------------------------------------------------------------------------
// MFMA skinny GEMM v2: single-wave blocks, no LDS, no barriers.
// Block (64 thr) = 1 wave owning one 32-col tile and one k-slice of 320
// (20 steps of k16). 3-way bf16 split: AhBh + AlBh + AhBl.
// 4-buffer rotating prefetch, depth 3 (24 loads in flight/wave).
// A (x) from xsrc (K,32) — L2-resident; B (weights) straight from global,
// 8 row-strided dword loads per step (256 B/instr coalesced).
// atomic=0: P[(so*32+row)*pstride+col] = acc  (split-K partials)
// atomic=1: atomicAdd(&P[row*pstride+col], acc)  (direct to out)
// Frag maps (verified R5): A[m=ln][k=kl+j], B[k=kl+j][n=ln],
// D: col=ln, row=(r&3)+8*(r>>2)+4*(lane>>5).
__global__ __launch_bounds__(64) void gemm_mfma(const float* __restrict__ W0,
                                                const float* __restrict__ W1,
                                                int wsplit, int wstride,
                                                const float* __restrict__ xsrc,
                                                float* __restrict__ P,
                                                int pstride, int ncb,
                                                int atomic) {
  const int cb   = blockIdx.x % ncb;
  const int so   = blockIdx.x / ncb;
  const int lane = threadIdx.x & 63;
  const int c0   = cb * 32;
  const float* __restrict__ W = (c0 < wsplit) ? W0 : W1;
  const int wc0  = (c0 < wsplit) ? c0 : c0 - wsplit;
  const int kw   = so * 320;
  const int kl   = (lane >> 5) * 8;          // 0 or 8
  const int ln   = lane & 31;

  const float* __restrict__ ap = xsrc + (size_t)(kw + kl) * BB + ln;
  const float* __restrict__ wp = W + (size_t)(kw + kl) * wstride + wc0 + ln;

  float ab[4][8], bb[4][8];
#pragma unroll
  for (int p = 0; p < 3; ++p) {
#pragma unroll
    for (int j = 0; j < 8; ++j) {
      ab[p][j] = ap[(size_t)(p * 16 + j) * BB];
      bb[p][j] = wp[(size_t)(p * 16 + j) * wstride];
    }
  }

  f32x16 acc;
#pragma unroll
  for (int i = 0; i < 16; ++i) acc[i] = 0.f;

#pragma unroll
  for (int s = 0; s < 20; ++s) {
    if (s < 17) {
      const int pn = (s + 3) & 3;
#pragma unroll
      for (int j = 0; j < 8; ++j) {
        ab[pn][j] = ap[(size_t)((s + 3) * 16 + j) * BB];
        bb[pn][j] = wp[(size_t)((s + 3) * 16 + j) * wstride];
      }
    }
    const int pc = s & 3;
    short8 ah, al, bh, bl;
    split8(ab[pc], ah, al);
    split8(bb[pc], bh, bl);
    acc = __builtin_amdgcn_mfma_f32_32x32x16_bf16(BC(ah), BC(bh), acc, 0, 0, 0);
    acc = __builtin_amdgcn_mfma_f32_32x32x16_bf16(BC(al), BC(bh), acc, 0, 0, 0);
    acc = __builtin_amdgcn_mfma_f32_32x32x16_bf16(BC(ah), BC(bl), acc, 0, 0, 0);
  }

  if (atomic) {
#pragma unroll
    for (int r = 0; r < 16; ++r) {
      int row = (r & 3) + 8 * (r >> 2) + 4 * (lane >> 5);
      atomicAdd(&P[(size_t)row * pstride + c0 + ln], acc[r]);
    }
  } else {
#pragma unroll
    for (int r = 0; r < 16; ++r) {
      int row = (r & 3) + 8 * (r >> 2) + 4 * (lane >> 5);
      P[((size_t)(so * 32 + row)) * pstride + c0 + ln] = acc[r];
    }
  }
}

// ---------------------------------------------------------------------------
// K1b: reduce the 8 outer partials, fuse conv(4-tap)+silu -> xt, silu -> res.
__global__ __launch_bounds__(256) void k1b_epilogue(const float* __restrict__ P1,
                                                    const float* __restrict__ cs,
                                                    const float* __restrict__ cw,
                                                    const float* __restrict__ cbv,
                                                    float* __restrict__ xt,
                                                    float* __restrict__ res) {
  int g = blockIdx.x * 256 + threadIdx.x;     // 0..163839
  int e = g % EE;
  int b = g / EE;
  float xs = 0.f, xm = 0.f;
#pragma unroll
  for (int so = 0; so < 8; ++so) {
    xs += P1[((size_t)(so * BB + b)) * 10240 + e];
    xm += P1[((size_t)(so * BB + b)) * 10240 + EE + e];
  }
  size_t be = (size_t)b * EE + e;
  const size_t T = (size_t)BB * EE;
  float conv = cs[be] * cw[be] + cs[T + be] * cw[T + be] +
               cs[2 * T + be] * cw[2 * T + be] + xs * cw[3 * T + be] + cbv[be];
  float sig = 1.f / (1.f + expf(-conv));
  xt[be] = conv * sig;
  float sm = 1.f / (1.f + expf(-xm));
  res[be] = xm * sm;
}

// ---------------------------------------------------------------------------
// K2: dbc = xt @ Wx  (32 x 5120 x 192). 192 blocks = 3 cb x 64 k-splits.
__global__ __launch_bounds__(256) void k2_dbc(const float* __restrict__ xt,
                                              const float* __restrict__ Wx,
                                              float* __restrict__ dbc) {
  const int bid  = blockIdx.x;
  const int cbi  = bid % 3;
  const int so   = bid / 3;                   // 0..63
  const int lane = threadIdx.x & 63;
  const int j    = cbi * 64 + lane;           // 0..191
  const int k0   = so * 80 + (int)(threadIdx.x >> 6) * 20;

  float acc[BB];
#pragma unroll
  for (int b = 0; b < BB; ++b) acc[b] = 0.f;

  for (int kk = 0; kk < 20; kk += 4) {
    int k = k0 + kk;
    float w0 = Wx[(size_t)(k + 0) * 192 + j];
    float w1 = Wx[(size_t)(k + 1) * 192 + j];
    float w2 = Wx[(size_t)(k + 2) * 192 + j];
    float w3 = Wx[(size_t)(k + 3) * 192 + j];
#pragma unroll
    for (int b = 0; b < BB; ++b) acc[b] = fmaf(xt[(size_t)b * EE + k + 0], w0, acc[b]);
#pragma unroll
    for (int b = 0; b < BB; ++b) acc[b] = fmaf(xt[(size_t)b * EE + k + 1], w1, acc[b]);
#pragma unroll
    for (int b = 0; b < BB; ++b) acc[b] = fmaf(xt[(size_t)b * EE + k + 2], w2, acc[b]);
#pragma unroll
    for (int b = 0; b < BB; ++b) acc[b] = fmaf(xt[(size_t)b * EE + k + 3], w3, acc[b]);
  }

  __shared__ float red2[4][64][17];
  const int ksid = threadIdx.x >> 6;
#pragma unroll
  for (int half = 0; half < 2; ++half) {
    __syncthreads();
#pragma unroll
    for (int i = 0; i < 16; ++i) red2[ksid][lane][i] = acc[half * 16 + i];
    __syncthreads();
#pragma unroll
    for (int jj = 0; jj < 4; ++jj) {
      int bi = ksid * 4 + jj;
      float v = red2[0][lane][bi] + red2[1][lane][bi] +
                red2[2][lane][bi] + red2[3][lane][bi];
      int b = half * 16 + bi;
      atomicAdd(&dbc[b * 192 + j], v);
    }
  }
}

// ---------------------------------------------------------------------------
// K3: dt-GEMM (K=160, Wdt tile async-staged to LDS) + softplus + SSM step
// + D*xt + residual mul -> zT (E,B). Also zeroes `out` for gemm2's atomics.
__global__ __launch_bounds__(256) void k3_ssm(const float* __restrict__ dbc,
                                              const float* __restrict__ Wdt,
                                              const float* __restrict__ dt_bias,
                                              const float* __restrict__ A_log,
                                              const float* __restrict__ Dvec,
                                              const float* __restrict__ h,
                                              const float* __restrict__ xt,
                                              const float* __restrict__ res,
                                              float* __restrict__ zT,
                                              float* __restrict__ out) {
  __shared__ float sw[10240];                 // 160 x 64 Wdt tile
  const int eb   = blockIdx.x % 80;
  const int bg   = blockIdx.x / 80;           // 0..3
  const int lane = threadIdx.x & 63;
  const int wv   = __builtin_amdgcn_readfirstlane((int)(threadIdx.x >> 6));
  const int e    = eb * 64 + lane;
  const int bq   = bg * 4 + wv;               // 0..15
  const int b0   = bq * 2, b1 = b0 + 1;

  out[blockIdx.x * 256 + threadIdx.x] = 0.f;  // 320*256 == 32*2560

  {
    const int rg = lane >> 4, cg = (lane & 15) * 4;
#pragma unroll
    for (int j = 0; j < 10; ++j) {
      int r = wv * 40 + j * 4 + rg;
      g2l16(Wdt + (size_t)r * EE + eb * 64 + cg, sw + (wv * 40 + j * 4) * 64);
    }
  }
  __syncthreads();                            // barrier drains vmcnt -> DMA landed

  float a0 = 0.f, a1 = 0.f;
  const float* __restrict__ d0 = dbc + b0 * 192;
  const float* __restrict__ d1 = dbc + b1 * 192;
#pragma unroll 4
  for (int r = 0; r < 160; ++r) {
    float w = sw[r * 64 + lane];
    a0 = fmaf(d0[r], w, a0);
    a1 = fmaf(d1[r], w, a1);
  }

  float An[16];
#pragma unroll
  for (int n = 0; n < 16; ++n) An[n] = -expf(A_log[e * 16 + n]);
  const float bias = dt_bias[e];
  const float Dv = Dvec[e];

#pragma unroll
  for (int t = 0; t < 2; ++t) {
    int b = t ? b1 : b0;
    float a = t ? a1 : a0;
    float v = a + bias;
    float dt = (v > 20.f) ? v : log1pf(expf(v));
    size_t be = (size_t)b * EE + e;
    float xb = xt[be];
    const float* __restrict__ hb = h + be * 16;
    const float* __restrict__ Bm = dbc + b * 192 + 160;
    const float* __restrict__ Cm = dbc + b * 192 + 176;
    float y = 0.f;
#pragma unroll
    for (int n = 0; n < 16; ++n) {
      float dA = expf(dt * An[n]);
      float hn = fmaf(hb[n], dA, dt * Bm[n] * xb);
      y = fmaf(hn, Cm[n], y);
    }
    y = fmaf(Dv, xb, y);
    zT[e * BB + b] = y * res[be];
  }
}

// ---------------------------------------------------------------------------
extern "C" void kernel_launch(void* const* d_in, const int* in_sizes, int n_in,
                              void* d_out, int out_size, void* d_ws, size_t ws_size,
                              hipStream_t stream) {
  const float* x       = (const float*)d_in[0];
  const float* Wssm    = (const float*)d_in[1];
  const float* Wmlp    = (const float*)d_in[2];
  const float* Wout    = (const float*)d_in[3];
  const float* conv_w  = (const float*)d_in[4];
  const float* conv_b  = (const float*)d_in[5];
  const float* conv_st = (const float*)d_in[6];
  const float* Wx      = (const float*)d_in[7];
  const float* Wdt     = (const float*)d_in[8];
  const float* dt_bias = (const float*)d_in[9];
  const float* A_log   = (const float*)d_in[10];
  const float* Dvec    = (const float*)d_in[11];
  const float* h       = (const float*)d_in[12];
  float* out = (float*)d_out;

  float* ws = (float*)d_ws;
  float* xT  = ws;                       // 81,920
  float* P1  = xT  + 81920;              // 2,621,440  (8 splits x 32 x 10240)
  float* xt  = P1  + 2621440;            // 163,840
  float* res = xt  + 163840;             // 163,840
  float* dbc = res + 163840;             // 6,144
  float* zT  = dbc + 6144;               // 163,840   (total ~12.8 MB)

  hipLaunchKernelGGL(k0_prep,     dim3(320),  dim3(256), 0, stream, x, xT, dbc);
  // gemm1: 320 col-tiles x 8 k-splits, K=2560
  hipLaunchKernelGGL(gemm_mfma,   dim3(2560), dim3(64),  0, stream,
                     Wssm, Wmlp, EE, EE, xT, P1, 10240, 320, 0);
  hipLaunchKernelGGL(k1b_epilogue,dim3(640),  dim3(256), 0, stream, P1, conv_st, conv_w, conv_b, xt, res);
  hipLaunchKernelGGL(k2_dbc,      dim3(192),  dim3(256), 0, stream, xt, Wx, dbc);
  hipLaunchKernelGGL(k3_ssm,      dim3(320),  dim3(256), 0, stream, dbc, Wdt, dt_bias, A_log, Dvec, h, xt, res, zT, out);
  // gemm2: 80 col-tiles x 16 k-splits, K=5120, atomicAdd into out
  hipLaunchKernelGGL(gemm_mfma,   dim3(1280), dim3(64),  0, stream,
                     Wout, Wout, 1 << 30, DD, zT, out, DD, 80, 1);
}